// Round 20
// baseline (151.250 us; speedup 1.0000x reference)
//
#include <hip/hip_runtime.h>
#include <hip/hip_bf16.h>
#include <math.h>

#define B_ 32
#define N_ 4096
#define D_ 64
#define T_ 12
#define EPS_ 1e-7f
#define ESTR 72   // e-plane LDS row stride in SHORTS (144B, 16B-aligned)

typedef float4 f4;
#define LD4(p) (*(const float4*)(p))

typedef __attribute__((ext_vector_type(8))) short short8;
typedef __attribute__((ext_vector_type(4))) short s4b;
typedef __attribute__((ext_vector_type(4))) float f32x4;
#define MFMA(a, b, c)   __builtin_amdgcn_mfma_f32_16x16x32_bf16(a, b, c, 0, 0, 0)
#define MFMA16(a, b, c) __builtin_amdgcn_mfma_f32_16x16x16bf16_1k(a, b, c, 0, 0, 0)

// weight blob offsets (shorts) in global wblob
#define OFF_C1H 0
#define OFF_C1L 8192
#define OFF_B1H 16384
#define OFF_B1L 24576
#define OFF_C2TH 32768
#define OFF_C2TL 36864
#define OFF_B2TH 40960
#define OFF_B2TL 45056
#define OFF_E2TH 49152
#define OFF_E2TL 53248
#define WBLOB_SHORTS 57344

// fp32 -> bf16 hi (RNE) + bf16 lo (RNE of remainder): a ~= hi + lo.
// Standard casts so the backend can pair conversions into v_cvt_pk_bf16_f32.
__device__ __forceinline__ void splitbf(float a, short& h, short& l) {
    __hip_bfloat16 hb = __float2bfloat16(a);
    const float hf = __bfloat162float(hb);
    __hip_bfloat16 lb = __float2bfloat16(a - hf);
    h = __builtin_bit_cast(short, hb);
    l = __builtin_bit_cast(short, lb);
}

// sigma: involutive feature permutation for e-storage (swap bits[5:4]<->[3:2])
__device__ __forceinline__ int sigma_(int f) {
    return (((f >> 2) & 3) << 4) | (((f >> 4) & 3) << 2) | (f & 3);
}

// ---------------------------------------------------------------------------
// Prep (parallel): 0-31 w1 packs, 32-47 w2^T packs, 48-63 emb w2^T, 64 contrib.
// ---------------------------------------------------------------------------
__global__ void prep_kernel(
    const float* __restrict__ cn_w1, const float* __restrict__ cn_w2,
    const float* __restrict__ bn_w1, const float* __restrict__ bn_w2,
    const float* __restrict__ bn_b1, const float* __restrict__ label_emb,
    const float* __restrict__ emb_w2,
    short* __restrict__ wblob, float* __restrict__ contrib)
{
    const int bid = blockIdx.x, tid = threadIdx.x;
    if (bid < 32) {                                  // w1 packs (K=128)
        const int idx = bid * 256 + tid;
        const int e = idx & 7, l = (idx >> 3) & 63, fb = idx >> 9;
        const int kt = fb >> 2, mt = fb & 3;
        const int f_lin = (kt & 1) * 32 + (l >> 4) * 8 + e;
        const int k = (kt >> 1) * 64 + sigma_(f_lin);
        const int n = mt * 16 + (l & 15);
        short h, lo;
        splitbf(cn_w1[k * 64 + n], h, lo);
        wblob[OFF_C1H + idx] = h; wblob[OFF_C1L + idx] = lo;
        splitbf(bn_w1[k * 64 + n], h, lo);
        wblob[OFF_B1H + idx] = h; wblob[OFF_B1L + idx] = lo;
    } else if (bid < 48) {                           // w2^T packs (16x16x16 A)
        const int idx = (bid - 32) * 256 + tid;
        const int e = idx & 3, l = (idx >> 2) & 63, fb = idx >> 8;
        const int ks = fb >> 2, mt2 = fb & 3;
        const int k = ks * 16 + (l >> 4) * 4 + e;
        const int n = mt2 * 16 + (l & 15);
        short h, lo;
        splitbf(cn_w2[k * 64 + n], h, lo);
        wblob[OFF_C2TH + idx] = h; wblob[OFF_C2TL + idx] = lo;
        splitbf(bn_w2[k * 64 + n], h, lo);
        wblob[OFF_B2TH + idx] = h; wblob[OFF_B2TL + idx] = lo;
    } else if (bid < 64) {                           // emb w2^T packs
        const int idx = (bid - 48) * 256 + tid;
        const int e = idx & 3, l = (idx >> 2) & 63, fb = idx >> 8;
        const int ks = fb >> 2, mt2 = fb & 3;
        const int k = ks * 16 + (l >> 4) * 4 + e;
        const int n = mt2 * 16 + (l & 15);
        short h, lo;
        splitbf(emb_w2[k * 64 + n], h, lo);
        wblob[OFF_E2TH + idx] = h; wblob[OFF_E2TL + idx] = lo;
    } else if (tid < 128) {                          // contrib
        const int c = tid >> 6, n = tid & 63;
        float s = bn_b1[n];
#pragma unroll 8
        for (int kk = 0; kk < 64; ++kk)
            s = fmaf(label_emb[c * 64 + kk], bn_w1[(128 + kk) * 64 + n], s);
        contrib[c * 64 + n] = s;
    }
}

// ---------------------------------------------------------------------------
// Fused HEAD: emb + stages t=0..4, all intermediates in LDS (run-major rows:
// pair d -> rows 2d,2d+1 at every stage). 1024 blocks x 256 thr (4 waves:
// net = wid>>1, sg = wid&1). Writes stage-4 e/v to global. W1 in regs.
// ---------------------------------------------------------------------------
__global__ __launch_bounds__(256, 2) void fused_head(
    const int* __restrict__ x, const float* __restrict__ y,
    const float* __restrict__ emb_w1, const float* __restrict__ emb_b1,
    const float* __restrict__ emb_b2,
    short* __restrict__ eo_hi, short* __restrict__ eo_lo, int* __restrict__ v_out,
    const short* __restrict__ wblob,
    const float* __restrict__ cn_b1, const float* __restrict__ cn_b2,
    const float* __restrict__ bn_b2, const float* __restrict__ contrib,
    const float* __restrict__ llr_w, const float* __restrict__ llr_b,
    float* __restrict__ loss_out, float2* __restrict__ pscr)
{
    __shared__ __align__(16) short w2lds[16384];       // 32 KB (cn|bn w2t)
    __shared__ __align__(16) short ehl[2][128 * ESTR]; // e hi/lo planes
    __shared__ int v_lds[128];
    __shared__ __align__(16) float cst[704];
    const int tid = threadIdx.x;
    {
        uint4* dst = (uint4*)w2lds;
        const uint4* src = (const uint4*)(wblob + OFF_C2TH);
#pragma unroll
        for (int i = 0; i < 8; ++i)
            dst[tid + i * 256] = src[tid + i * 256];
    }
    if (tid < 128) {
        cst[tid] = contrib[tid];
        cst[320 + tid] = llr_w[tid];
        cst[448 + tid] = emb_w1[tid];
    }
    if (tid < 64) {
        cst[128 + tid] = cn_b1[tid];
        cst[192 + tid] = cn_b2[tid];
        cst[256 + tid] = bn_b2[tid];
        cst[576 + tid] = emb_b1[tid];
        cst[640 + tid] = emb_b2[tid];
    }

    const int lane = tid & 63;
    const int pr = lane & 15, kg = lane >> 4;
    const int wid = tid >> 6;
    const int net = wid >> 1, sg = wid & 1;
    const int w2b = net * 8192;
    const int gpos0 = blockIdx.x * 128;        // flat position base
    const int b     = gpos0 >> 12;
    const int posb  = gpos0 & (N_ - 1);        // in-batch position base

    short8 w1h[16], w1l[16];
    {
        const short* wh = wblob + (net ? OFF_B1H : OFF_C1H);
        const short* wl = wblob + (net ? OFF_B1L : OFF_C1L);
#pragma unroll
        for (int f = 0; f < 16; ++f) {
            const int fo = (f * 64 + lane) * 8;
            w1h[f] = *(const short8*)(wh + fo);
            w1l[f] = *(const short8*)(wl + fo);
        }
    }
    const float* b2c = net ? (cst + 256) : (cst + 192);
    __syncthreads();   // cst/w2lds ready

    // ======== emb phase: 2 positions per thread, e -> LDS rows ========
    {
        s4b we2h[16], we2l[16];
#pragma unroll
        for (int f = 0; f < 16; ++f) {
            const int fo4 = (f * 64 + lane) * 4;
            we2h[f] = *(const s4b*)(wblob + OFF_E2TH + fo4);
            we2l[f] = *(const s4b*)(wblob + OFF_E2TL + fo4);
        }
#pragma unroll
        for (int sub = 0; sub < 2; ++sub) {
            const int pos = wid * 32 + sub * 16 + pr;
            const float2 yv = *(const float2*)(y + 2 * (gpos0 + pos));
            s4b hh[4], hl[4];
#pragma unroll
            for (int ks = 0; ks < 4; ++ks)
#pragma unroll
                for (int e2 = 0; e2 < 4; ++e2) {
                    const int f = ks * 16 + kg * 4 + e2;
                    const float hv = fmaxf(
                        fmaf(yv.y, cst[512 + f], fmaf(yv.x, cst[448 + f], cst[576 + f])), 0.f);
                    short sh, sl2; splitbf(hv, sh, sl2);
                    hh[ks][e2] = sh; hl[ks][e2] = sl2;
                }
            f32x4 o[4];
#pragma unroll
            for (int mt2 = 0; mt2 < 4; ++mt2) {
                const f4 bb = LD4(cst + 640 + mt2 * 16 + kg * 4);
                o[mt2] = (f32x4){bb.x, bb.y, bb.z, bb.w};
            }
#pragma unroll
            for (int ks = 0; ks < 4; ++ks)
#pragma unroll
                for (int mt2 = 0; mt2 < 4; ++mt2) {
                    o[mt2] = MFMA16(we2h[ks * 4 + mt2], hh[ks], o[mt2]);
                    o[mt2] = MFMA16(we2l[ks * 4 + mt2], hh[ks], o[mt2]);
                    o[mt2] = MFMA16(we2h[ks * 4 + mt2], hl[ks], o[mt2]);
                }
            union { short sv[16]; uint4 v[2]; } ph, pl;
#pragma unroll
            for (int mt2 = 0; mt2 < 4; ++mt2)
#pragma unroll
                for (int e2 = 0; e2 < 4; ++e2) {
                    short sh, sl2;
                    splitbf(o[mt2][e2], sh, sl2);
                    ph.sv[mt2 * 4 + e2] = sh; pl.sv[mt2 * 4 + e2] = sl2;
                }
            short* dh = &ehl[0][pos * ESTR + kg * 16];
            short* dl = &ehl[1][pos * ESTR + kg * 16];
            *(uint4*)dh       = ph.v[0];
            *(uint4*)(dh + 8) = ph.v[1];
            *(uint4*)dl       = pl.v[0];
            *(uint4*)(dl + 8) = pl.v[1];
            if (kg == 0) v_lds[pos] = x[gpos0 + pos];
        }
    }
    __syncthreads();

    // ======== stages s = 0..4 ========
#pragma unroll 1
    for (int s = 0; s < 5; ++s) {
        const int prl    = 6 - s;            // log2(pairs per run)
        const int Lhs    = 2048 >> s;
        const int rowlen = 128 >> s;

        int qA[2], CnA[2], orowA[2], v1A[2], vxA[2];
        f32x4 acc[2][4];
#pragma unroll
        for (int st = 0; st < 2; ++st) {
            const int d = sg * 32 + st * 16 + pr;
            const int r = d >> prl;
            const int q = d & ((1 << prl) - 1);
            int G = posb;
            for (int i = 0; i < s; ++i) {
                const int Lhi = 2048 >> i;
                G = G - ((G >> 1) & (Lhi - 1)) + (((r >> (s - 1 - i)) & 1) ? Lhi : 0);
            }
            qA[st]  = q;
            CnA[st] = G - ((G >> 1) & (Lhs - 1));
            orowA[st] = r * rowlen + net * (rowlen >> 1) + q;
            const int v0 = v_lds[2 * d], v1 = v_lds[2 * d + 1];
            v1A[st] = v1; vxA[st] = (v0 ^ v1) & 1;
#pragma unroll
            for (int mt = 0; mt < 4; ++mt) {
                if (net) {
                    const f4 cb = LD4(cst + vxA[st] * 64 + mt * 16 + kg * 4);
                    acc[st][mt] = (f32x4){cb.x, cb.y, cb.z, cb.w};
                } else {
                    const f4 bc = LD4(cst + 128 + mt * 16 + kg * 4);
                    acc[st][mt] = (f32x4){bc.x, bc.y, bc.z, bc.w};
                }
            }
        }

#pragma unroll
        for (int kt = 0; kt < 4; ++kt) {
            short8 Eh[2], El[2];
#pragma unroll
            for (int st = 0; st < 2; ++st) {
                const int d = sg * 32 + st * 16 + pr;
                const int off = (2 * d + (kt >> 1)) * ESTR + (kt & 1) * 32 + kg * 8;
                Eh[st] = *(const short8*)&ehl[0][off];
                El[st] = *(const short8*)&ehl[1][off];
            }
#pragma unroll
            for (int mt = 0; mt < 4; ++mt) {
                const short8 wh = w1h[kt * 4 + mt], wl = w1l[kt * 4 + mt];
#pragma unroll
                for (int st = 0; st < 2; ++st) {
                    acc[st][mt] = MFMA(wh, Eh[st], acc[st][mt]);
                    acc[st][mt] = MFMA(wl, Eh[st], acc[st][mt]);
                    acc[st][mt] = MFMA(wh, El[st], acc[st][mt]);
                }
            }
        }

        s4b hh[2][4], hl[2][4];
#pragma unroll
        for (int st = 0; st < 2; ++st)
#pragma unroll
            for (int ks = 0; ks < 4; ++ks)
#pragma unroll
                for (int e2 = 0; e2 < 4; ++e2) {
                    short sh, sl2;
                    splitbf(fmaxf(acc[st][ks][e2], 0.f), sh, sl2);
                    hh[st][ks][e2] = sh; hl[st][ks][e2] = sl2;
                }

        f32x4 o[2][4];
#pragma unroll
        for (int mt2 = 0; mt2 < 4; ++mt2) {
            const f4 bb = LD4(b2c + mt2 * 16 + kg * 4);
#pragma unroll
            for (int st = 0; st < 2; ++st) o[st][mt2] = (f32x4){bb.x, bb.y, bb.z, bb.w};
        }
#pragma unroll
        for (int ks = 0; ks < 4; ++ks)
#pragma unroll
            for (int mt2 = 0; mt2 < 4; ++mt2) {
                const int fo4 = ((ks * 4 + mt2) * 64 + lane) * 4;
                const s4b wh = *(const s4b*)(w2lds + w2b + fo4);
                const s4b wl = *(const s4b*)(w2lds + w2b + 4096 + fo4);
#pragma unroll
                for (int st = 0; st < 2; ++st) {
                    o[st][mt2] = MFMA16(wh, hh[st][ks], o[st][mt2]);
                    o[st][mt2] = MFMA16(wl, hh[st][ks], o[st][mt2]);
                    o[st][mt2] = MFMA16(wh, hl[st][ks], o[st][mt2]);
                }
            }

        uint4 pkh[2][2], pkl[2][2];
        int vnA[2];
#pragma unroll
        for (int st = 0; st < 2; ++st) {
            const int io = CnA[st] + qA[st] + net * Lhs;
            vnA[st] = net ? v1A[st] : vxA[st];

            float z0 = 0.f, z1 = 0.f;
            union { short sv[16]; uint4 v[2]; } ph, pl;
#pragma unroll
            for (int mt2 = 0; mt2 < 4; ++mt2) {
#pragma unroll
                for (int e2 = 0; e2 < 4; ++e2) {
                    short sh, sl2;
                    splitbf(o[st][mt2][e2], sh, sl2);
                    ph.sv[mt2 * 4 + e2] = sh; pl.sv[mt2 * 4 + e2] = sl2;
                }
                const int f0 = mt2 * 16 + kg * 4;
                const f4 wA = LD4(cst + 320 + 2 * f0);
                const f4 wB = LD4(cst + 320 + 2 * f0 + 4);
                z0 += o[st][mt2][0] * wA.x + o[st][mt2][1] * wA.z +
                      o[st][mt2][2] * wB.x + o[st][mt2][3] * wB.z;
                z1 += o[st][mt2][0] * wA.y + o[st][mt2][1] * wA.w +
                      o[st][mt2][2] * wB.y + o[st][mt2][3] * wB.w;
            }
            pkh[st][0] = ph.v[0]; pkh[st][1] = ph.v[1];
            pkl[st][0] = pl.v[0]; pkl[st][1] = pl.v[1];
            z0 += __shfl_xor(z0, 16); z1 += __shfl_xor(z1, 16);
            z0 += __shfl_xor(z0, 32); z1 += __shfl_xor(z1, 32);

            if (kg == 0) {
                const float zz0 = z0 + llr_b[0], zz1 = z1 + llr_b[1];
                const float m   = fmaxf(zz0, zz1);
                const float ex0 = expf(zz0 - m), ex1 = expf(zz1 - m);
                const float inv = 1.0f / (ex0 + ex1);
                const float p0s = ex0 * inv, p1s = ex1 * inv;
                const float c0  = fminf(fmaxf(p0s, EPS_), 1.0f - EPS_);
                const float c1  = fminf(fmaxf(p1s, EPS_), 1.0f - EPS_);
                const int   lab = net ? (v1A[st] & 1) : vxA[st];
                const float loss = -logf(lab ? c1 : c0);
                loss_out[(b * T_ + s) * N_ + io] = loss;
                pscr[(size_t)(b * T_ + s) * N_ + io] = make_float2(p0s, p1s);
            }

            if (s == 4) {   // final: write e/v to global
                const size_t eb = (size_t)(b * N_ + io) * D_ + kg * 16;
                *(uint4*)(eo_hi + eb)     = ph.v[0];
                *(uint4*)(eo_hi + eb + 8) = ph.v[1];
                *(uint4*)(eo_lo + eb)     = pl.v[0];
                *(uint4*)(eo_lo + eb + 8) = pl.v[1];
                if (kg == 0) v_out[b * N_ + io] = vnA[st];
            }
        }

        if (s < 4) {
            __syncthreads();   // all e/v reads of this stage complete
#pragma unroll
            for (int st = 0; st < 2; ++st) {
                short* dh = &ehl[0][orowA[st] * ESTR + kg * 16];
                short* dl = &ehl[1][orowA[st] * ESTR + kg * 16];
                *(uint4*)dh       = pkh[st][0];
                *(uint4*)(dh + 8) = pkh[st][1];
                *(uint4*)dl       = pkl[st][0];
                *(uint4*)(dl + 8) = pkl[st][1];
                if (kg == 0) v_lds[orowA[st]] = vnA[st];
            }
            __syncthreads();   // writes visible for next stage
        }
    }
}

// ---------------------------------------------------------------------------
// Fused tail (t = 5..11): proven template + folded pred transpose.
// ---------------------------------------------------------------------------
__global__ __launch_bounds__(256, 2) void fused_tail(
    const short* __restrict__ e_hi, const short* __restrict__ e_lo,
    const int* __restrict__ v_in,
    const short* __restrict__ wblob,
    const float* __restrict__ cn_b1, const float* __restrict__ cn_b2,
    const float* __restrict__ bn_b2, const float* __restrict__ contrib,
    const float* __restrict__ llr_w, const float* __restrict__ llr_b,
    float* __restrict__ loss_out, float2* __restrict__ pscr,
    float* __restrict__ pred1, float* __restrict__ pred2)
{
    __shared__ __align__(16) short w2lds[16384];       // 32 KB
    __shared__ __align__(16) short ehl[2][128 * ESTR]; // 2 x 18KB hi/lo planes
    __shared__ int v_lds[128];
    __shared__ __align__(16) float cst[448];
    const int tid = threadIdx.x;
    {
        uint4* dst = (uint4*)w2lds;
        const uint4* src = (const uint4*)(wblob + OFF_C2TH);
#pragma unroll
        for (int i = 0; i < 8; ++i)
            dst[tid + i * 256] = src[tid + i * 256];
    }
    if (tid < 128) { cst[tid] = contrib[tid]; cst[320 + tid] = llr_w[tid]; }
    if (tid < 64) {
        cst[128 + tid] = cn_b1[tid];
        cst[192 + tid] = cn_b2[tid];
        cst[256 + tid] = bn_b2[tid];
    }
    const int b = blockIdx.x >> 5, ch = blockIdx.x & 31;
    const int base_row = b * N_ + ch * 128;
    {
        const int r = tid >> 1, seg = tid & 1;
        const size_t g = (size_t)(base_row + r) * D_ + seg * 32;
#pragma unroll
        for (int pl = 0; pl < 2; ++pl) {
            const short* sp = (pl ? e_lo : e_hi) + g;
            short* dp = &ehl[pl][r * ESTR + seg * 32];
            *(uint4*)dp        = *(const uint4*)sp;
            *(uint4*)(dp + 8)  = *(const uint4*)(sp + 8);
            *(uint4*)(dp + 16) = *(const uint4*)(sp + 16);
            *(uint4*)(dp + 24) = *(const uint4*)(sp + 24);
        }
        if (tid < 128) v_lds[tid] = v_in[base_row + tid];
    }

    const int lane = tid & 63;
    const int pr = lane & 15, kg = lane >> 4;
    const int wid = tid >> 6;
    const int net = wid >> 1, sg = wid & 1;
    const int w2b = net * 8192;

    short8 w1h[16], w1l[16];
    {
        const short* wh = wblob + (net ? OFF_B1H : OFF_C1H);
        const short* wl = wblob + (net ? OFF_B1L : OFF_C1L);
#pragma unroll
        for (int f = 0; f < 16; ++f) {
            const int fo = (f * 64 + lane) * 8;
            w1h[f] = *(const short8*)(wh + fo);
            w1l[f] = *(const short8*)(wl + fo);
        }
    }
    const float* b2c = net ? (cst + 256) : (cst + 192);
    __syncthreads();

    int Lh = 64;
#pragma unroll 1
    for (int t = 5; t < 12; ++t, Lh >>= 1) {
        int pA[2], v1A[2], vxA[2];
        f32x4 acc[2][4];
#pragma unroll
        for (int s = 0; s < 2; ++s) {
            const int p = sg * 32 + s * 16 + pr;
            pA[s] = p;
            const int v0 = v_lds[2 * p], v1 = v_lds[2 * p + 1];
            v1A[s] = v1; vxA[s] = (v0 ^ v1) & 1;
#pragma unroll
            for (int mt = 0; mt < 4; ++mt) {
                if (net) {
                    const f4 cb = LD4(cst + vxA[s] * 64 + mt * 16 + kg * 4);
                    acc[s][mt] = (f32x4){cb.x, cb.y, cb.z, cb.w};
                } else {
                    const f4 bc = LD4(cst + 128 + mt * 16 + kg * 4);
                    acc[s][mt] = (f32x4){bc.x, bc.y, bc.z, bc.w};
                }
            }
        }

#pragma unroll
        for (int kt = 0; kt < 4; ++kt) {
            short8 Eh[2], El[2];
#pragma unroll
            for (int s = 0; s < 2; ++s) {
                const int off = (2 * pA[s] + (kt >> 1)) * ESTR + (kt & 1) * 32 + kg * 8;
                Eh[s] = *(const short8*)&ehl[0][off];
                El[s] = *(const short8*)&ehl[1][off];
            }
#pragma unroll
            for (int mt = 0; mt < 4; ++mt) {
                const short8 wh = w1h[kt * 4 + mt], wl = w1l[kt * 4 + mt];
#pragma unroll
                for (int s = 0; s < 2; ++s) {
                    acc[s][mt] = MFMA(wh, Eh[s], acc[s][mt]);
                    acc[s][mt] = MFMA(wl, Eh[s], acc[s][mt]);
                    acc[s][mt] = MFMA(wh, El[s], acc[s][mt]);
                }
            }
        }

        s4b hh[2][4], hl[2][4];
#pragma unroll
        for (int s = 0; s < 2; ++s)
#pragma unroll
            for (int ks = 0; ks < 4; ++ks)
#pragma unroll
                for (int e2 = 0; e2 < 4; ++e2) {
                    short sh, sl2;
                    splitbf(fmaxf(acc[s][ks][e2], 0.f), sh, sl2);
                    hh[s][ks][e2] = sh; hl[s][ks][e2] = sl2;
                }

        f32x4 o[2][4];
#pragma unroll
        for (int mt2 = 0; mt2 < 4; ++mt2) {
            const f4 bb = LD4(b2c + mt2 * 16 + kg * 4);
#pragma unroll
            for (int s = 0; s < 2; ++s) o[s][mt2] = (f32x4){bb.x, bb.y, bb.z, bb.w};
        }
#pragma unroll
        for (int ks = 0; ks < 4; ++ks)
#pragma unroll
            for (int mt2 = 0; mt2 < 4; ++mt2) {
                const int fo4 = ((ks * 4 + mt2) * 64 + lane) * 4;
                const s4b wh = *(const s4b*)(w2lds + w2b + fo4);
                const s4b wl = *(const s4b*)(w2lds + w2b + 4096 + fo4);
#pragma unroll
                for (int s = 0; s < 2; ++s) {
                    o[s][mt2] = MFMA16(wh, hh[s][ks], o[s][mt2]);
                    o[s][mt2] = MFMA16(wl, hh[s][ks], o[s][mt2]);
                    o[s][mt2] = MFMA16(wh, hl[s][ks], o[s][mt2]);
                }
            }

        int iolA[2], vnA[2];
        uint4 pkh[2][2], pkl[2][2];
#pragma unroll
        for (int s = 0; s < 2; ++s) {
            const int p = pA[s];
            const int j = p & (Lh - 1);
            const int iol = 2 * p - j + (net ? Lh : 0);
            iolA[s] = iol;
            vnA[s]  = net ? v1A[s] : vxA[s];

            float z0 = 0.f, z1 = 0.f;
            union { short sv[16]; uint4 v[2]; } ph, pl;
#pragma unroll
            for (int mt2 = 0; mt2 < 4; ++mt2) {
#pragma unroll
                for (int e2 = 0; e2 < 4; ++e2) {
                    short sh, sl2;
                    splitbf(o[s][mt2][e2], sh, sl2);
                    ph.sv[mt2 * 4 + e2] = sh; pl.sv[mt2 * 4 + e2] = sl2;
                }
                const int f0 = mt2 * 16 + kg * 4;
                const f4 wA = LD4(cst + 320 + 2 * f0);
                const f4 wB = LD4(cst + 320 + 2 * f0 + 4);
                z0 += o[s][mt2][0] * wA.x + o[s][mt2][1] * wA.z +
                      o[s][mt2][2] * wB.x + o[s][mt2][3] * wB.z;
                z1 += o[s][mt2][0] * wA.y + o[s][mt2][1] * wA.w +
                      o[s][mt2][2] * wB.y + o[s][mt2][3] * wB.w;
            }
            pkh[s][0] = ph.v[0]; pkh[s][1] = ph.v[1];
            pkl[s][0] = pl.v[0]; pkl[s][1] = pl.v[1];
            z0 += __shfl_xor(z0, 16); z1 += __shfl_xor(z1, 16);
            z0 += __shfl_xor(z0, 32); z1 += __shfl_xor(z1, 32);

            if (kg == 0) {
                const int io = ch * 128 + iol;
                const float zz0 = z0 + llr_b[0], zz1 = z1 + llr_b[1];
                const float m   = fmaxf(zz0, zz1);
                const float ex0 = expf(zz0 - m), ex1 = expf(zz1 - m);
                const float inv = 1.0f / (ex0 + ex1);
                const float p0s = ex0 * inv, p1s = ex1 * inv;
                const float c0  = fminf(fmaxf(p0s, EPS_), 1.0f - EPS_);
                const float c1  = fminf(fmaxf(p1s, EPS_), 1.0f - EPS_);
                const int   lab = net ? (v1A[s] & 1) : vxA[s];
                const float loss = -logf(lab ? c1 : c0);
                loss_out[(b * T_ + t) * N_ + io] = loss;
                pscr[(size_t)(b * T_ + t) * N_ + io] = make_float2(p0s, p1s);
            }
        }
        __syncthreads();

#pragma unroll
        for (int s = 0; s < 2; ++s) {
            short* dh = &ehl[0][iolA[s] * ESTR + kg * 16];
            short* dl = &ehl[1][iolA[s] * ESTR + kg * 16];
            *(uint4*)dh       = pkh[s][0];
            *(uint4*)(dh + 8) = pkh[s][1];
            *(uint4*)dl       = pkl[s][0];
            *(uint4*)(dl + 8) = pkl[s][1];
            if (kg == 0) v_lds[iolA[s]] = vnA[s];
        }
        __syncthreads();
    }

    // ---- folded pred transpose: this block's 128 positions ----
    if (tid < 128) {
        const int io  = ch * 128 + tid;
        const int idx = b * N_ + io;
        float2 v[T_];
#pragma unroll
        for (int t = 0; t < T_; ++t)
            v[t] = pscr[(size_t)(b * T_ + t) * N_ + io];
        float* d1 = pred1 + (size_t)idx * (T_ * 2);
        float* d2 = pred2 + (size_t)idx * (T_ * 2);
#pragma unroll
        for (int q = 0; q < 6; ++q) {
            const f4 w = make_float4(v[2 * q].x, v[2 * q].y, v[2 * q + 1].x, v[2 * q + 1].y);
            *(f4*)(d1 + 4 * q) = w;
            *(f4*)(d2 + 4 * q) = w;
        }
    }
}

// ---------------------------------------------------------------------------
extern "C" void kernel_launch(void* const* d_in, const int* in_sizes, int n_in,
                              void* d_out, int out_size, void* d_ws, size_t ws_size,
                              hipStream_t stream)
{
    const int*   x      = (const int*)  d_in[0];
    const float* y      = (const float*)d_in[1];
    const float* emb_w1 = (const float*)d_in[2];
    const float* emb_b1 = (const float*)d_in[3];
    const float* emb_w2 = (const float*)d_in[4];
    const float* emb_b2 = (const float*)d_in[5];
    const float* cn_w1  = (const float*)d_in[6];
    const float* cn_b1  = (const float*)d_in[7];
    const float* cn_w2  = (const float*)d_in[8];
    const float* cn_b2  = (const float*)d_in[9];
    const float* bn_w1  = (const float*)d_in[10];
    const float* bn_b1  = (const float*)d_in[11];
    const float* bn_w2  = (const float*)d_in[12];
    const float* bn_b2  = (const float*)d_in[13];
    const float* llr_w  = (const float*)d_in[14];
    const float* llr_b  = (const float*)d_in[15];
    const float* label_emb = (const float*)d_in[16];

    float* out      = (float*)d_out;
    float* loss_out = out;
    float* pred1    = out + (size_t)B_ * T_ * N_;
    float* pred2    = pred1 + (size_t)B_ * N_ * T_ * 2;

    const size_t EPLANE = (size_t)B_ * N_ * D_;
    short* eh_a = (short*)d_ws;
    short* el_a = eh_a + EPLANE;
    int*   v_a  = (int*)(el_a + EPLANE);
    float2* pscr = (float2*)(v_a + B_ * N_);
    short* wblob = (short*)(pscr + (size_t)B_ * T_ * N_);
    float* contrib = (float*)(wblob + WBLOB_SHORTS);

    prep_kernel<<<dim3(65), dim3(256), 0, stream>>>(
        cn_w1, cn_w2, bn_w1, bn_w2, bn_b1, label_emb, emb_w2, wblob, contrib);

    fused_head<<<dim3(1024), dim3(256), 0, stream>>>(
        x, y, emb_w1, emb_b1, emb_b2,
        eh_a, el_a, v_a, wblob,
        cn_b1, cn_b2, bn_b2, contrib, llr_w, llr_b,
        loss_out, pscr);

    fused_tail<<<dim3(1024), dim3(256), 0, stream>>>(
        eh_a, el_a, v_a, wblob,
        cn_b1, cn_b2, bn_b2, contrib, llr_w, llr_b,
        loss_out, pscr, pred1, pred2);
}

// Round 21
// 148.033 us; speedup vs baseline: 1.0217x; 1.0217x over previous
//
#include <hip/hip_runtime.h>
#include <math.h>

#define B_ 32
#define N_ 4096
#define D_ 64
#define T_ 12
#define EPS_ 1e-7f
#define ESTR 72   // e-plane LDS row stride in SHORTS (144B, 16B-aligned)

typedef float4 f4;
#define LD4(p) (*(const float4*)(p))

typedef __attribute__((ext_vector_type(8))) short short8;
typedef __attribute__((ext_vector_type(4))) short s4b;
typedef __attribute__((ext_vector_type(4))) float f32x4;
#define MFMA(a, b, c)   __builtin_amdgcn_mfma_f32_16x16x32_bf16(a, b, c, 0, 0, 0)
#define MFMA16(a, b, c) __builtin_amdgcn_mfma_f32_16x16x16bf16_1k(a, b, c, 0, 0, 0)

// weight blob offsets (shorts) in global wblob
#define OFF_C1H 0
#define OFF_C1L 8192
#define OFF_B1H 16384
#define OFF_B1L 24576
#define OFF_C2TH 32768
#define OFF_C2TL 36864
#define OFF_B2TH 40960
#define OFF_B2TL 45056
#define OFF_E2TH 49152
#define OFF_E2TL 53248
#define WBLOB_SHORTS 57344

__device__ __forceinline__ void splitbf(float a, short& h, short& l) {
    unsigned x = __float_as_uint(a);
    h = (short)(x >> 16);
    float r = a - __uint_as_float(x & 0xffff0000u);
    l = (short)(__float_as_uint(r) >> 16);
}

// sigma: involutive feature permutation for e-storage (swap bits[5:4]<->[3:2])
__device__ __forceinline__ int sigma_(int f) {
    return (((f >> 2) & 3) << 4) | (((f >> 4) & 3) << 2) | (f & 3);
}

// ---------------------------------------------------------------------------
// Prep (parallel): 0-31 w1 packs, 32-47 w2^T packs, 48-63 emb w2^T, 64 contrib.
// ---------------------------------------------------------------------------
__global__ void prep_kernel(
    const float* __restrict__ cn_w1, const float* __restrict__ cn_w2,
    const float* __restrict__ bn_w1, const float* __restrict__ bn_w2,
    const float* __restrict__ bn_b1, const float* __restrict__ label_emb,
    const float* __restrict__ emb_w2,
    short* __restrict__ wblob, float* __restrict__ contrib)
{
    const int bid = blockIdx.x, tid = threadIdx.x;
    if (bid < 32) {                                  // w1 packs (K=128)
        const int idx = bid * 256 + tid;
        const int e = idx & 7, l = (idx >> 3) & 63, fb = idx >> 9;
        const int kt = fb >> 2, mt = fb & 3;
        const int f_lin = (kt & 1) * 32 + (l >> 4) * 8 + e;
        const int k = (kt >> 1) * 64 + sigma_(f_lin);
        const int n = mt * 16 + (l & 15);
        short h, lo;
        splitbf(cn_w1[k * 64 + n], h, lo);
        wblob[OFF_C1H + idx] = h; wblob[OFF_C1L + idx] = lo;
        splitbf(bn_w1[k * 64 + n], h, lo);
        wblob[OFF_B1H + idx] = h; wblob[OFF_B1L + idx] = lo;
    } else if (bid < 48) {                           // w2^T packs (16x16x16 A)
        const int idx = (bid - 32) * 256 + tid;
        const int e = idx & 3, l = (idx >> 2) & 63, fb = idx >> 8;
        const int ks = fb >> 2, mt2 = fb & 3;
        const int k = ks * 16 + (l >> 4) * 4 + e;
        const int n = mt2 * 16 + (l & 15);
        short h, lo;
        splitbf(cn_w2[k * 64 + n], h, lo);
        wblob[OFF_C2TH + idx] = h; wblob[OFF_C2TL + idx] = lo;
        splitbf(bn_w2[k * 64 + n], h, lo);
        wblob[OFF_B2TH + idx] = h; wblob[OFF_B2TL + idx] = lo;
    } else if (bid < 64) {                           // emb w2^T packs
        const int idx = (bid - 48) * 256 + tid;
        const int e = idx & 3, l = (idx >> 2) & 63, fb = idx >> 8;
        const int ks = fb >> 2, mt2 = fb & 3;
        const int k = ks * 16 + (l >> 4) * 4 + e;
        const int n = mt2 * 16 + (l & 15);
        short h, lo;
        splitbf(emb_w2[k * 64 + n], h, lo);
        wblob[OFF_E2TH + idx] = h; wblob[OFF_E2TL + idx] = lo;
    } else if (tid < 128) {                          // contrib
        const int c = tid >> 6, n = tid & 63;
        float s = bn_b1[n];
#pragma unroll 8
        for (int kk = 0; kk < 64; ++kk)
            s = fmaf(label_emb[c * 64 + kk], bn_w1[(128 + kk) * 64 + n], s);
        contrib[c * 64 + n] = s;
    }
}

// ---------------------------------------------------------------------------
// Fused HEAD: emb + stages t=0..4, all intermediates in LDS (run-major rows:
// pair d -> rows 2d,2d+1 at every stage). 1024 blocks x 256 thr (4 waves:
// net = wid>>1, sg = wid&1). Writes stage-4 e/v to global. W1 in regs.
// ---------------------------------------------------------------------------
__global__ __launch_bounds__(256, 2) void fused_head(
    const int* __restrict__ x, const float* __restrict__ y,
    const float* __restrict__ emb_w1, const float* __restrict__ emb_b1,
    const float* __restrict__ emb_b2,
    short* __restrict__ eo_hi, short* __restrict__ eo_lo, int* __restrict__ v_out,
    const short* __restrict__ wblob,
    const float* __restrict__ cn_b1, const float* __restrict__ cn_b2,
    const float* __restrict__ bn_b2, const float* __restrict__ contrib,
    const float* __restrict__ llr_w, const float* __restrict__ llr_b,
    float* __restrict__ loss_out, float2* __restrict__ pscr)
{
    __shared__ __align__(16) short w2lds[16384];       // 32 KB (cn|bn w2t)
    __shared__ __align__(16) short ehl[2][128 * ESTR]; // e hi/lo planes
    __shared__ int v_lds[128];
    __shared__ __align__(16) float cst[704];
    const int tid = threadIdx.x;
    {
        uint4* dst = (uint4*)w2lds;
        const uint4* src = (const uint4*)(wblob + OFF_C2TH);
#pragma unroll
        for (int i = 0; i < 8; ++i)
            dst[tid + i * 256] = src[tid + i * 256];
    }
    if (tid < 128) {
        cst[tid] = contrib[tid];
        cst[320 + tid] = llr_w[tid];
        cst[448 + tid] = emb_w1[tid];
    }
    if (tid < 64) {
        cst[128 + tid] = cn_b1[tid];
        cst[192 + tid] = cn_b2[tid];
        cst[256 + tid] = bn_b2[tid];
        cst[576 + tid] = emb_b1[tid];
        cst[640 + tid] = emb_b2[tid];
    }

    const int lane = tid & 63;
    const int pr = lane & 15, kg = lane >> 4;
    const int wid = tid >> 6;
    const int net = wid >> 1, sg = wid & 1;
    const int w2b = net * 8192;
    const int gpos0 = blockIdx.x * 128;        // flat position base
    const int b     = gpos0 >> 12;
    const int posb  = gpos0 & (N_ - 1);        // in-batch position base

    short8 w1h[16], w1l[16];
    {
        const short* wh = wblob + (net ? OFF_B1H : OFF_C1H);
        const short* wl = wblob + (net ? OFF_B1L : OFF_C1L);
#pragma unroll
        for (int f = 0; f < 16; ++f) {
            const int fo = (f * 64 + lane) * 8;
            w1h[f] = *(const short8*)(wh + fo);
            w1l[f] = *(const short8*)(wl + fo);
        }
    }
    const float* b2c = net ? (cst + 256) : (cst + 192);
    __syncthreads();   // cst/w2lds ready

    // ======== emb phase: 2 positions per thread, e -> LDS rows ========
    {
        s4b we2h[16], we2l[16];
#pragma unroll
        for (int f = 0; f < 16; ++f) {
            const int fo4 = (f * 64 + lane) * 4;
            we2h[f] = *(const s4b*)(wblob + OFF_E2TH + fo4);
            we2l[f] = *(const s4b*)(wblob + OFF_E2TL + fo4);
        }
#pragma unroll
        for (int sub = 0; sub < 2; ++sub) {
            const int pos = wid * 32 + sub * 16 + pr;
            const float2 yv = *(const float2*)(y + 2 * (gpos0 + pos));
            s4b hh[4], hl[4];
#pragma unroll
            for (int ks = 0; ks < 4; ++ks)
#pragma unroll
                for (int e2 = 0; e2 < 4; ++e2) {
                    const int f = ks * 16 + kg * 4 + e2;
                    const float hv = fmaxf(
                        fmaf(yv.y, cst[512 + f], fmaf(yv.x, cst[448 + f], cst[576 + f])), 0.f);
                    short sh, sl2; splitbf(hv, sh, sl2);
                    hh[ks][e2] = sh; hl[ks][e2] = sl2;
                }
            f32x4 o[4];
#pragma unroll
            for (int mt2 = 0; mt2 < 4; ++mt2) {
                const f4 bb = LD4(cst + 640 + mt2 * 16 + kg * 4);
                o[mt2] = (f32x4){bb.x, bb.y, bb.z, bb.w};
            }
#pragma unroll
            for (int ks = 0; ks < 4; ++ks)
#pragma unroll
                for (int mt2 = 0; mt2 < 4; ++mt2) {
                    o[mt2] = MFMA16(we2h[ks * 4 + mt2], hh[ks], o[mt2]);
                    o[mt2] = MFMA16(we2l[ks * 4 + mt2], hh[ks], o[mt2]);
                    o[mt2] = MFMA16(we2h[ks * 4 + mt2], hl[ks], o[mt2]);
                }
            union { short sv[16]; uint4 v[2]; } ph, pl;
#pragma unroll
            for (int mt2 = 0; mt2 < 4; ++mt2)
#pragma unroll
                for (int e2 = 0; e2 < 4; ++e2) {
                    short sh, sl2;
                    splitbf(o[mt2][e2], sh, sl2);
                    ph.sv[mt2 * 4 + e2] = sh; pl.sv[mt2 * 4 + e2] = sl2;
                }
            short* dh = &ehl[0][pos * ESTR + kg * 16];
            short* dl = &ehl[1][pos * ESTR + kg * 16];
            *(uint4*)dh       = ph.v[0];
            *(uint4*)(dh + 8) = ph.v[1];
            *(uint4*)dl       = pl.v[0];
            *(uint4*)(dl + 8) = pl.v[1];
            if (kg == 0) v_lds[pos] = x[gpos0 + pos];
        }
    }
    __syncthreads();

    // ======== stages s = 0..4 ========
#pragma unroll 1
    for (int s = 0; s < 5; ++s) {
        const int prl    = 6 - s;            // log2(pairs per run)
        const int Lhs    = 2048 >> s;
        const int rowlen = 128 >> s;

        int qA[2], CnA[2], orowA[2], v1A[2], vxA[2];
        f32x4 acc[2][4];
#pragma unroll
        for (int st = 0; st < 2; ++st) {
            const int d = sg * 32 + st * 16 + pr;
            const int r = d >> prl;
            const int q = d & ((1 << prl) - 1);
            int G = posb;
            for (int i = 0; i < s; ++i) {
                const int Lhi = 2048 >> i;
                G = G - ((G >> 1) & (Lhi - 1)) + (((r >> (s - 1 - i)) & 1) ? Lhi : 0);
            }
            qA[st]  = q;
            CnA[st] = G - ((G >> 1) & (Lhs - 1));
            orowA[st] = r * rowlen + net * (rowlen >> 1) + q;
            const int v0 = v_lds[2 * d], v1 = v_lds[2 * d + 1];
            v1A[st] = v1; vxA[st] = (v0 ^ v1) & 1;
#pragma unroll
            for (int mt = 0; mt < 4; ++mt) {
                if (net) {
                    const f4 cb = LD4(cst + vxA[st] * 64 + mt * 16 + kg * 4);
                    acc[st][mt] = (f32x4){cb.x, cb.y, cb.z, cb.w};
                } else {
                    const f4 bc = LD4(cst + 128 + mt * 16 + kg * 4);
                    acc[st][mt] = (f32x4){bc.x, bc.y, bc.z, bc.w};
                }
            }
        }

#pragma unroll
        for (int kt = 0; kt < 4; ++kt) {
            short8 Eh[2], El[2];
#pragma unroll
            for (int st = 0; st < 2; ++st) {
                const int d = sg * 32 + st * 16 + pr;
                const int off = (2 * d + (kt >> 1)) * ESTR + (kt & 1) * 32 + kg * 8;
                Eh[st] = *(const short8*)&ehl[0][off];
                El[st] = *(const short8*)&ehl[1][off];
            }
#pragma unroll
            for (int mt = 0; mt < 4; ++mt) {
                const short8 wh = w1h[kt * 4 + mt], wl = w1l[kt * 4 + mt];
#pragma unroll
                for (int st = 0; st < 2; ++st) {
                    acc[st][mt] = MFMA(wh, Eh[st], acc[st][mt]);
                    acc[st][mt] = MFMA(wl, Eh[st], acc[st][mt]);
                    acc[st][mt] = MFMA(wh, El[st], acc[st][mt]);
                }
            }
        }

        s4b hh[2][4], hl[2][4];
#pragma unroll
        for (int st = 0; st < 2; ++st)
#pragma unroll
            for (int ks = 0; ks < 4; ++ks)
#pragma unroll
                for (int e2 = 0; e2 < 4; ++e2) {
                    short sh, sl2;
                    splitbf(fmaxf(acc[st][ks][e2], 0.f), sh, sl2);
                    hh[st][ks][e2] = sh; hl[st][ks][e2] = sl2;
                }

        f32x4 o[2][4];
#pragma unroll
        for (int mt2 = 0; mt2 < 4; ++mt2) {
            const f4 bb = LD4(b2c + mt2 * 16 + kg * 4);
#pragma unroll
            for (int st = 0; st < 2; ++st) o[st][mt2] = (f32x4){bb.x, bb.y, bb.z, bb.w};
        }
#pragma unroll
        for (int ks = 0; ks < 4; ++ks)
#pragma unroll
            for (int mt2 = 0; mt2 < 4; ++mt2) {
                const int fo4 = ((ks * 4 + mt2) * 64 + lane) * 4;
                const s4b wh = *(const s4b*)(w2lds + w2b + fo4);
                const s4b wl = *(const s4b*)(w2lds + w2b + 4096 + fo4);
#pragma unroll
                for (int st = 0; st < 2; ++st) {
                    o[st][mt2] = MFMA16(wh, hh[st][ks], o[st][mt2]);
                    o[st][mt2] = MFMA16(wl, hh[st][ks], o[st][mt2]);
                    o[st][mt2] = MFMA16(wh, hl[st][ks], o[st][mt2]);
                }
            }

        uint4 pkh[2][2], pkl[2][2];
        int vnA[2];
#pragma unroll
        for (int st = 0; st < 2; ++st) {
            const int io = CnA[st] + qA[st] + net * Lhs;
            vnA[st] = net ? v1A[st] : vxA[st];

            float z0 = 0.f, z1 = 0.f;
            union { short sv[16]; uint4 v[2]; } ph, pl;
#pragma unroll
            for (int mt2 = 0; mt2 < 4; ++mt2) {
#pragma unroll
                for (int e2 = 0; e2 < 4; ++e2) {
                    short sh, sl2;
                    splitbf(o[st][mt2][e2], sh, sl2);
                    ph.sv[mt2 * 4 + e2] = sh; pl.sv[mt2 * 4 + e2] = sl2;
                }
                const int f0 = mt2 * 16 + kg * 4;
                const f4 wA = LD4(cst + 320 + 2 * f0);
                const f4 wB = LD4(cst + 320 + 2 * f0 + 4);
                z0 += o[st][mt2][0] * wA.x + o[st][mt2][1] * wA.z +
                      o[st][mt2][2] * wB.x + o[st][mt2][3] * wB.z;
                z1 += o[st][mt2][0] * wA.y + o[st][mt2][1] * wA.w +
                      o[st][mt2][2] * wB.y + o[st][mt2][3] * wB.w;
            }
            pkh[st][0] = ph.v[0]; pkh[st][1] = ph.v[1];
            pkl[st][0] = pl.v[0]; pkl[st][1] = pl.v[1];
            z0 += __shfl_xor(z0, 16); z1 += __shfl_xor(z1, 16);
            z0 += __shfl_xor(z0, 32); z1 += __shfl_xor(z1, 32);

            if (kg == 0) {
                const float zz0 = z0 + llr_b[0], zz1 = z1 + llr_b[1];
                const float m   = fmaxf(zz0, zz1);
                const float ex0 = expf(zz0 - m), ex1 = expf(zz1 - m);
                const float inv = 1.0f / (ex0 + ex1);
                const float p0s = ex0 * inv, p1s = ex1 * inv;
                const float c0  = fminf(fmaxf(p0s, EPS_), 1.0f - EPS_);
                const float c1  = fminf(fmaxf(p1s, EPS_), 1.0f - EPS_);
                const int   lab = net ? (v1A[st] & 1) : vxA[st];
                const float loss = -logf(lab ? c1 : c0);
                loss_out[(b * T_ + s) * N_ + io] = loss;
                pscr[(size_t)(b * T_ + s) * N_ + io] = make_float2(p0s, p1s);
            }

            if (s == 4) {   // final: write e/v to global
                const size_t eb = (size_t)(b * N_ + io) * D_ + kg * 16;
                *(uint4*)(eo_hi + eb)     = ph.v[0];
                *(uint4*)(eo_hi + eb + 8) = ph.v[1];
                *(uint4*)(eo_lo + eb)     = pl.v[0];
                *(uint4*)(eo_lo + eb + 8) = pl.v[1];
                if (kg == 0) v_out[b * N_ + io] = vnA[st];
            }
        }

        if (s < 4) {
            __syncthreads();   // all e/v reads of this stage complete
#pragma unroll
            for (int st = 0; st < 2; ++st) {
                short* dh = &ehl[0][orowA[st] * ESTR + kg * 16];
                short* dl = &ehl[1][orowA[st] * ESTR + kg * 16];
                *(uint4*)dh       = pkh[st][0];
                *(uint4*)(dh + 8) = pkh[st][1];
                *(uint4*)dl       = pkl[st][0];
                *(uint4*)(dl + 8) = pkl[st][1];
                if (kg == 0) v_lds[orowA[st]] = vnA[st];
            }
            __syncthreads();   // writes visible for next stage
        }
    }
}

// ---------------------------------------------------------------------------
// Fused tail (t = 5..11): proven template + folded pred transpose.
// ---------------------------------------------------------------------------
__global__ __launch_bounds__(256, 2) void fused_tail(
    const short* __restrict__ e_hi, const short* __restrict__ e_lo,
    const int* __restrict__ v_in,
    const short* __restrict__ wblob,
    const float* __restrict__ cn_b1, const float* __restrict__ cn_b2,
    const float* __restrict__ bn_b2, const float* __restrict__ contrib,
    const float* __restrict__ llr_w, const float* __restrict__ llr_b,
    float* __restrict__ loss_out, float2* __restrict__ pscr,
    float* __restrict__ pred1, float* __restrict__ pred2)
{
    __shared__ __align__(16) short w2lds[16384];       // 32 KB
    __shared__ __align__(16) short ehl[2][128 * ESTR]; // 2 x 18KB hi/lo planes
    __shared__ int v_lds[128];
    __shared__ __align__(16) float cst[448];
    const int tid = threadIdx.x;
    {
        uint4* dst = (uint4*)w2lds;
        const uint4* src = (const uint4*)(wblob + OFF_C2TH);
#pragma unroll
        for (int i = 0; i < 8; ++i)
            dst[tid + i * 256] = src[tid + i * 256];
    }
    if (tid < 128) { cst[tid] = contrib[tid]; cst[320 + tid] = llr_w[tid]; }
    if (tid < 64) {
        cst[128 + tid] = cn_b1[tid];
        cst[192 + tid] = cn_b2[tid];
        cst[256 + tid] = bn_b2[tid];
    }
    const int b = blockIdx.x >> 5, ch = blockIdx.x & 31;
    const int base_row = b * N_ + ch * 128;
    {
        const int r = tid >> 1, seg = tid & 1;
        const size_t g = (size_t)(base_row + r) * D_ + seg * 32;
#pragma unroll
        for (int pl = 0; pl < 2; ++pl) {
            const short* sp = (pl ? e_lo : e_hi) + g;
            short* dp = &ehl[pl][r * ESTR + seg * 32];
            *(uint4*)dp        = *(const uint4*)sp;
            *(uint4*)(dp + 8)  = *(const uint4*)(sp + 8);
            *(uint4*)(dp + 16) = *(const uint4*)(sp + 16);
            *(uint4*)(dp + 24) = *(const uint4*)(sp + 24);
        }
        if (tid < 128) v_lds[tid] = v_in[base_row + tid];
    }

    const int lane = tid & 63;
    const int pr = lane & 15, kg = lane >> 4;
    const int wid = tid >> 6;
    const int net = wid >> 1, sg = wid & 1;
    const int w2b = net * 8192;

    short8 w1h[16], w1l[16];
    {
        const short* wh = wblob + (net ? OFF_B1H : OFF_C1H);
        const short* wl = wblob + (net ? OFF_B1L : OFF_C1L);
#pragma unroll
        for (int f = 0; f < 16; ++f) {
            const int fo = (f * 64 + lane) * 8;
            w1h[f] = *(const short8*)(wh + fo);
            w1l[f] = *(const short8*)(wl + fo);
        }
    }
    const float* b2c = net ? (cst + 256) : (cst + 192);
    __syncthreads();

    int Lh = 64;
#pragma unroll 1
    for (int t = 5; t < 12; ++t, Lh >>= 1) {
        int pA[2], v1A[2], vxA[2];
        f32x4 acc[2][4];
#pragma unroll
        for (int s = 0; s < 2; ++s) {
            const int p = sg * 32 + s * 16 + pr;
            pA[s] = p;
            const int v0 = v_lds[2 * p], v1 = v_lds[2 * p + 1];
            v1A[s] = v1; vxA[s] = (v0 ^ v1) & 1;
#pragma unroll
            for (int mt = 0; mt < 4; ++mt) {
                if (net) {
                    const f4 cb = LD4(cst + vxA[s] * 64 + mt * 16 + kg * 4);
                    acc[s][mt] = (f32x4){cb.x, cb.y, cb.z, cb.w};
                } else {
                    const f4 bc = LD4(cst + 128 + mt * 16 + kg * 4);
                    acc[s][mt] = (f32x4){bc.x, bc.y, bc.z, bc.w};
                }
            }
        }

#pragma unroll
        for (int kt = 0; kt < 4; ++kt) {
            short8 Eh[2], El[2];
#pragma unroll
            for (int s = 0; s < 2; ++s) {
                const int off = (2 * pA[s] + (kt >> 1)) * ESTR + (kt & 1) * 32 + kg * 8;
                Eh[s] = *(const short8*)&ehl[0][off];
                El[s] = *(const short8*)&ehl[1][off];
            }
#pragma unroll
            for (int mt = 0; mt < 4; ++mt) {
                const short8 wh = w1h[kt * 4 + mt], wl = w1l[kt * 4 + mt];
#pragma unroll
                for (int s = 0; s < 2; ++s) {
                    acc[s][mt] = MFMA(wh, Eh[s], acc[s][mt]);
                    acc[s][mt] = MFMA(wl, Eh[s], acc[s][mt]);
                    acc[s][mt] = MFMA(wh, El[s], acc[s][mt]);
                }
            }
        }

        s4b hh[2][4], hl[2][4];
#pragma unroll
        for (int s = 0; s < 2; ++s)
#pragma unroll
            for (int ks = 0; ks < 4; ++ks)
#pragma unroll
                for (int e2 = 0; e2 < 4; ++e2) {
                    short sh, sl2;
                    splitbf(fmaxf(acc[s][ks][e2], 0.f), sh, sl2);
                    hh[s][ks][e2] = sh; hl[s][ks][e2] = sl2;
                }

        f32x4 o[2][4];
#pragma unroll
        for (int mt2 = 0; mt2 < 4; ++mt2) {
            const f4 bb = LD4(b2c + mt2 * 16 + kg * 4);
#pragma unroll
            for (int s = 0; s < 2; ++s) o[s][mt2] = (f32x4){bb.x, bb.y, bb.z, bb.w};
        }
#pragma unroll
        for (int ks = 0; ks < 4; ++ks)
#pragma unroll
            for (int mt2 = 0; mt2 < 4; ++mt2) {
                const int fo4 = ((ks * 4 + mt2) * 64 + lane) * 4;
                const s4b wh = *(const s4b*)(w2lds + w2b + fo4);
                const s4b wl = *(const s4b*)(w2lds + w2b + 4096 + fo4);
#pragma unroll
                for (int s = 0; s < 2; ++s) {
                    o[s][mt2] = MFMA16(wh, hh[s][ks], o[s][mt2]);
                    o[s][mt2] = MFMA16(wl, hh[s][ks], o[s][mt2]);
                    o[s][mt2] = MFMA16(wh, hl[s][ks], o[s][mt2]);
                }
            }

        int iolA[2], vnA[2];
        uint4 pkh[2][2], pkl[2][2];
#pragma unroll
        for (int s = 0; s < 2; ++s) {
            const int p = pA[s];
            const int j = p & (Lh - 1);
            const int iol = 2 * p - j + (net ? Lh : 0);
            iolA[s] = iol;
            vnA[s]  = net ? v1A[s] : vxA[s];

            float z0 = 0.f, z1 = 0.f;
            union { short sv[16]; uint4 v[2]; } ph, pl;
#pragma unroll
            for (int mt2 = 0; mt2 < 4; ++mt2) {
#pragma unroll
                for (int e2 = 0; e2 < 4; ++e2) {
                    short sh, sl2;
                    splitbf(o[s][mt2][e2], sh, sl2);
                    ph.sv[mt2 * 4 + e2] = sh; pl.sv[mt2 * 4 + e2] = sl2;
                }
                const int f0 = mt2 * 16 + kg * 4;
                const f4 wA = LD4(cst + 320 + 2 * f0);
                const f4 wB = LD4(cst + 320 + 2 * f0 + 4);
                z0 += o[s][mt2][0] * wA.x + o[s][mt2][1] * wA.z +
                      o[s][mt2][2] * wB.x + o[s][mt2][3] * wB.z;
                z1 += o[s][mt2][0] * wA.y + o[s][mt2][1] * wA.w +
                      o[s][mt2][2] * wB.y + o[s][mt2][3] * wB.w;
            }
            pkh[s][0] = ph.v[0]; pkh[s][1] = ph.v[1];
            pkl[s][0] = pl.v[0]; pkl[s][1] = pl.v[1];
            z0 += __shfl_xor(z0, 16); z1 += __shfl_xor(z1, 16);
            z0 += __shfl_xor(z0, 32); z1 += __shfl_xor(z1, 32);

            if (kg == 0) {
                const int io = ch * 128 + iol;
                const float zz0 = z0 + llr_b[0], zz1 = z1 + llr_b[1];
                const float m   = fmaxf(zz0, zz1);
                const float ex0 = expf(zz0 - m), ex1 = expf(zz1 - m);
                const float inv = 1.0f / (ex0 + ex1);
                const float p0s = ex0 * inv, p1s = ex1 * inv;
                const float c0  = fminf(fmaxf(p0s, EPS_), 1.0f - EPS_);
                const float c1  = fminf(fmaxf(p1s, EPS_), 1.0f - EPS_);
                const int   lab = net ? (v1A[s] & 1) : vxA[s];
                const float loss = -logf(lab ? c1 : c0);
                loss_out[(b * T_ + t) * N_ + io] = loss;
                pscr[(size_t)(b * T_ + t) * N_ + io] = make_float2(p0s, p1s);
            }
        }
        __syncthreads();

#pragma unroll
        for (int s = 0; s < 2; ++s) {
            short* dh = &ehl[0][iolA[s] * ESTR + kg * 16];
            short* dl = &ehl[1][iolA[s] * ESTR + kg * 16];
            *(uint4*)dh       = pkh[s][0];
            *(uint4*)(dh + 8) = pkh[s][1];
            *(uint4*)dl       = pkl[s][0];
            *(uint4*)(dl + 8) = pkl[s][1];
            if (kg == 0) v_lds[iolA[s]] = vnA[s];
        }
        __syncthreads();
    }

    // ---- folded pred transpose: this block's 128 positions ----
    if (tid < 128) {
        const int io  = ch * 128 + tid;
        const int idx = b * N_ + io;
        float2 v[T_];
#pragma unroll
        for (int t = 0; t < T_; ++t)
            v[t] = pscr[(size_t)(b * T_ + t) * N_ + io];
        float* d1 = pred1 + (size_t)idx * (T_ * 2);
        float* d2 = pred2 + (size_t)idx * (T_ * 2);
#pragma unroll
        for (int q = 0; q < 6; ++q) {
            const f4 w = make_float4(v[2 * q].x, v[2 * q].y, v[2 * q + 1].x, v[2 * q + 1].y);
            *(f4*)(d1 + 4 * q) = w;
            *(f4*)(d2 + 4 * q) = w;
        }
    }
}

// ---------------------------------------------------------------------------
extern "C" void kernel_launch(void* const* d_in, const int* in_sizes, int n_in,
                              void* d_out, int out_size, void* d_ws, size_t ws_size,
                              hipStream_t stream)
{
    const int*   x      = (const int*)  d_in[0];
    const float* y      = (const float*)d_in[1];
    const float* emb_w1 = (const float*)d_in[2];
    const float* emb_b1 = (const float*)d_in[3];
    const float* emb_w2 = (const float*)d_in[4];
    const float* emb_b2 = (const float*)d_in[5];
    const float* cn_w1  = (const float*)d_in[6];
    const float* cn_b1  = (const float*)d_in[7];
    const float* cn_w2  = (const float*)d_in[8];
    const float* cn_b2  = (const float*)d_in[9];
    const float* bn_w1  = (const float*)d_in[10];
    const float* bn_b1  = (const float*)d_in[11];
    const float* bn_w2  = (const float*)d_in[12];
    const float* bn_b2  = (const float*)d_in[13];
    const float* llr_w  = (const float*)d_in[14];
    const float* llr_b  = (const float*)d_in[15];
    const float* label_emb = (const float*)d_in[16];

    float* out      = (float*)d_out;
    float* loss_out = out;
    float* pred1    = out + (size_t)B_ * T_ * N_;
    float* pred2    = pred1 + (size_t)B_ * N_ * T_ * 2;

    const size_t EPLANE = (size_t)B_ * N_ * D_;
    short* eh_a = (short*)d_ws;
    short* el_a = eh_a + EPLANE;
    int*   v_a  = (int*)(el_a + EPLANE);
    float2* pscr = (float2*)(v_a + B_ * N_);
    short* wblob = (short*)(pscr + (size_t)B_ * T_ * N_);
    float* contrib = (float*)(wblob + WBLOB_SHORTS);

    prep_kernel<<<dim3(65), dim3(256), 0, stream>>>(
        cn_w1, cn_w2, bn_w1, bn_w2, bn_b1, label_emb, emb_w2, wblob, contrib);

    fused_head<<<dim3(1024), dim3(256), 0, stream>>>(
        x, y, emb_w1, emb_b1, emb_b2,
        eh_a, el_a, v_a, wblob,
        cn_b1, cn_b2, bn_b2, contrib, llr_w, llr_b,
        loss_out, pscr);

    fused_tail<<<dim3(1024), dim3(256), 0, stream>>>(
        eh_a, el_a, v_a, wblob,
        cn_b1, cn_b2, bn_b2, contrib, llr_w, llr_b,
        loss_out, pscr, pred1, pred2);
}